// Round 6
// baseline (10704.162 us; speedup 1.0000x reference)
//
#include <hip/hip_runtime.h>

#define TT 2048
#define BB 256
#define HID 64

typedef float f32x4 __attribute__((ext_vector_type(4)));

__device__ __forceinline__ float frcp(float x) { return __builtin_amdgcn_rcpf(x); }
__device__ __forceinline__ float fsig(float x) { return frcp(1.f + __expf(-x)); }
// tanh(x) = 1 - 2/(1+e^{2x}) : stable at +/-inf (no inf-inf)
__device__ __forceinline__ float ftanh(float x) { return 1.f - 2.f * frcp(1.f + __expf(2.f * x)); }

// Raw workgroup barrier: waits LDS ops only (lgkmcnt), does NOT drain vmcnt —
// global prefetch loads / h-stores stay in flight across the barrier.
__device__ __forceinline__ void wg_barrier_lds() {
    asm volatile("s_waitcnt lgkmcnt(0)" ::: "memory");
    __builtin_amdgcn_s_barrier();
    asm volatile("" ::: "memory");
}

// pre = in(R,K) @ W(256,K)^T + b_ih + b_hh  -> out(R,256)
// block: 256 threads, tile 64 rows x 256 cols, k-chunks of 16.  (layer 0 only)
__global__ __launch_bounds__(256, 2) void gemm_pre_k(
    const float* __restrict__ in, const float* __restrict__ W,
    const float* __restrict__ b_ih, const float* __restrict__ b_hh,
    float* __restrict__ out, int K)
{
    __shared__ __align__(16) float in_s[64][20];   // +4 pad keeps float4 align, breaks conflicts
    __shared__ __align__(16) float w_s[16][256];   // transposed W chunk: w_s[k][g]

    const int tid = threadIdx.x;
    const int tx = tid & 15, ty = tid >> 4;
    const long long row0 = (long long)blockIdx.x * 64;

    float4 bias[4];
    {
        const float4* bi4 = (const float4*)b_ih;
        const float4* bh4 = (const float4*)b_hh;
#pragma unroll
        for (int jj = 0; jj < 4; ++jj) {
            float4 a = bi4[tx * 4 + jj], b = bh4[tx * 4 + jj];
            bias[jj] = make_float4(a.x + b.x, a.y + b.y, a.z + b.z, a.w + b.w);
        }
    }

    float4 acc[4][4];
#pragma unroll
    for (int i = 0; i < 4; ++i)
#pragma unroll
        for (int j = 0; j < 4; ++j) acc[i][j] = make_float4(0.f, 0.f, 0.f, 0.f);

    const int rs = tid >> 2;   // 0..63 staging row
    const int kq = tid & 3;    // 0..3 staging k-quarter

    for (int kc = 0; kc < K; kc += 16) {
        __syncthreads();
        float4 iv = *(const float4*)(in + (row0 + rs) * K + kc + kq * 4);
        *(float4*)(&in_s[rs][kq * 4]) = iv;
        const float* wr = W + (long long)tid * K + kc;
        float4 w0 = ((const float4*)wr)[0];
        float4 w1 = ((const float4*)wr)[1];
        float4 w2 = ((const float4*)wr)[2];
        float4 w3 = ((const float4*)wr)[3];
        w_s[0][tid] = w0.x;  w_s[1][tid] = w0.y;  w_s[2][tid] = w0.z;  w_s[3][tid] = w0.w;
        w_s[4][tid] = w1.x;  w_s[5][tid] = w1.y;  w_s[6][tid] = w1.z;  w_s[7][tid] = w1.w;
        w_s[8][tid] = w2.x;  w_s[9][tid] = w2.y;  w_s[10][tid] = w2.z; w_s[11][tid] = w2.w;
        w_s[12][tid] = w3.x; w_s[13][tid] = w3.y; w_s[14][tid] = w3.z; w_s[15][tid] = w3.w;
        __syncthreads();

#pragma unroll
        for (int k2 = 0; k2 < 4; ++k2) {
            float4 a[4];
#pragma unroll
            for (int i = 0; i < 4; ++i) a[i] = *(const float4*)(&in_s[ty * 4 + i][k2 * 4]);
#pragma unroll
            for (int kk = 0; kk < 4; ++kk) {
                const int k = k2 * 4 + kk;
                float4 wv[4];
#pragma unroll
                for (int jj = 0; jj < 4; ++jj) wv[jj] = *(const float4*)(&w_s[k][tx * 16 + jj * 4]);
#pragma unroll
                for (int i = 0; i < 4; ++i) {
                    const float av = ((const float*)&a[i])[kk];
#pragma unroll
                    for (int jj = 0; jj < 4; ++jj) {
                        acc[i][jj].x += av * wv[jj].x;
                        acc[i][jj].y += av * wv[jj].y;
                        acc[i][jj].z += av * wv[jj].z;
                        acc[i][jj].w += av * wv[jj].w;
                    }
                }
            }
        }
    }

#pragma unroll
    for (int i = 0; i < 4; ++i) {
        float4* op = (float4*)(out + (row0 + ty * 4 + i) * 256 + tx * 16);
#pragma unroll
        for (int jj = 0; jj < 4; ++jj) {
            float4 v = acc[i][jj];
            v.x += bias[jj].x; v.y += bias[jj].y; v.z += bias[jj].z; v.w += bias[jj].w;
            op[jj] = v;
        }
    }
}

// Fused 3-layer recurrent kernel — systolic layer pipeline.
//  - one block per batch element, 768 threads = 12 waves = 3 layers x 4 gates.
//    Wave wv: layer L = wv>>2, gate type q = wv&3 (i,f,g,o). Lane j owns
//    h-index j -> weight rows W_hh[L][q*64+j] (+ W_ih[L][q*64+j] for L>0):
//    128 weight VGPRs/lane, the profile R5 proved arch-resident (132 VGPR).
//  - global step s: layer L processes local t = s-L. Both of its inputs
//    (h_{L-1}(t) and h_L(t-1)) were produced at step s-1 -> systolic skew.
//    Layers 1,2 compute W_ih.h in-register -> their standalone GEMMs die,
//    and rec wall time drops from 3*TT steps to TT+2.
//  - two lgkm-only barriers/step: BAR1 orders gate exchange (gx), BAR2 orders
//    the h broadcast (hX). vmcnt (layer-0 prefetch, layer-2 h store) never
//    drains at a barrier.
//  - 12 waves/CU = 3/SIMD; launch_bounds(768) caps VGPR at 170.
__global__ __launch_bounds__(768) void lstm_fused_k(
    const float* __restrict__ pre,      // [BB][TT][256] layer-0 pre (GEMM+bias)
    const float* __restrict__ whh0,
    const float* __restrict__ wih1, const float* __restrict__ whh1,
    const float* __restrict__ bih1, const float* __restrict__ bhh1,
    const float* __restrict__ wih2, const float* __restrict__ whh2,
    const float* __restrict__ bih2, const float* __restrict__ bhh2,
    float* __restrict__ h_out)          // [BB][TT][64] layer-2 h
{
    __shared__ __align__(16) float hX[3][HID];   // latest h per layer
    __shared__ float gx[3][4][HID];              // activated gates [L][q][j]

    const int tid = threadIdx.x;
    const int wv  = tid >> 6;      // 0..11
    const int L   = wv >> 2;       // layer 0..2
    const int q   = wv & 3;        // gate type: 0=i 1=f 2=g(tanh) 3=o
    const int j   = tid & 63;      // h index
    const int g   = q * HID + j;   // gate row
    const int b   = blockIdx.x;

    // ---- weights into registers (wave-uniform L branches) ----
    f32x4 whh_r[16];
    f32x4 wih_r[16];
    float bias = 0.f;
    {
        const float* whh = (L == 0) ? whh0 : (L == 1 ? whh1 : whh2);
        const f32x4* wr = (const f32x4*)(whh + (long long)g * HID);
#pragma unroll
        for (int k = 0; k < 16; ++k) whh_r[k] = wr[k];
        if (L > 0) {
            const float* wih = (L == 1) ? wih1 : wih2;
            const f32x4* wi = (const f32x4*)(wih + (long long)g * HID);
#pragma unroll
            for (int k = 0; k < 16; ++k) wih_r[k] = wi[k];
            bias = (L == 1) ? (bih1[g] + bhh1[g]) : (bih2[g] + bhh2[g]);
        } else {
#pragma unroll
            for (int k = 0; k < 16; ++k) wih_r[k] = (f32x4)(0.f);
        }
    }

    if (tid < 3 * HID) ((float*)hX)[tid] = 0.f;
    float c = 0.f;
    __syncthreads();

    // ---- layer-0 pre prefetch: 4 static slots, 1 float/step/lane ----
    const float* pq = pre + (long long)b * TT * 256 + g;
    float pb4[4];
#pragma unroll
    for (int u = 0; u < 4; ++u) pb4[u] = pq[u * 256];

    float* hop = h_out + (long long)b * TT * HID + j;
    const bool upd = (q == 0);

    for (int sb = 0; sb < TT + 4; sb += 4) {
        const float* pn = pq + (long long)(sb + 4) * 256;   // reload base (t+4)
#pragma unroll
        for (int u = 0; u < 4; ++u) {
            const int s = sb + u;
            const int t = s - L;
            const bool active = (t >= 0) && (t < TT);   // wave-uniform

            if (active) {
                f32x4 acc = (f32x4)(0.f);
                float gA;
                if (L == 0) {
                    const f32x4* hon = (const f32x4*)(&hX[0][0]);
#pragma unroll
                    for (int k = 0; k < 16; ++k) acc += whh_r[k] * hon[k];
                    gA = pb4[u];                         // slot u == t&3 (L=0)
                    if (sb + u + 4 < TT) pb4[u] = pn[u * 256];  // stays in flight
                } else {
                    const f32x4* hin = (const f32x4*)(&hX[L - 1][0]);
                    const f32x4* hon = (const f32x4*)(&hX[L][0]);
#pragma unroll
                    for (int k = 0; k < 16; ++k) {
                        acc += wih_r[k] * hin[k];        // wave-uniform broadcast
                        acc += whh_r[k] * hon[k];
                    }
                    gA = bias;
                }
                gA += (acc.x + acc.y) + (acc.z + acc.w);
                float a = (q == 2) ? ftanh(gA) : fsig(gA);
                gx[L][q][j] = a;                         // conflict-free
            }

            wg_barrier_lds();                            // BAR1: gates visible

            if (active && upd) {
                float iv = gx[L][0][j];
                float fv = gx[L][1][j];
                float gv = gx[L][2][j];
                float ov = gx[L][3][j];
                c = fv * c + iv * gv;
                float h = ov * ftanh(c);
                hX[L][j] = h;
                if (L == 2) hop[(long long)t * HID] = h; // fire-and-forget
            }

            wg_barrier_lds();                            // BAR2: h visible
        }
    }
}

// out(r) = h(r,:) . fc_w + fc_b   — trivial GEMV epilogue, off the critical path
__global__ __launch_bounds__(256) void fc_k(
    const float* __restrict__ h, const float* __restrict__ fc_w,
    const float* __restrict__ fc_b, float* __restrict__ out, long long R)
{
    __shared__ __align__(16) float w_s[HID];
    if (threadIdx.x < HID) w_s[threadIdx.x] = fc_w[threadIdx.x];
    __syncthreads();

    long long r = (long long)blockIdx.x * 256 + threadIdx.x;
    if (r >= R) return;

    const float4* hp = (const float4*)(h + r * HID);
    const float4* wp = (const float4*)w_s;
    float s0 = 0.f, s1 = 0.f, s2 = 0.f, s3 = 0.f;
#pragma unroll
    for (int k = 0; k < 16; ++k) {
        float4 hvv = hp[k];
        float4 wvv = wp[k];      // wave-uniform LDS broadcast
        s0 += hvv.x * wvv.x;
        s1 += hvv.y * wvv.y;
        s2 += hvv.z * wvv.z;
        s3 += hvv.w * wvv.w;
    }
    out[r] = (s0 + s1) + (s2 + s3) + fc_b[0];
}

extern "C" void kernel_launch(void* const* d_in, const int* in_sizes, int n_in,
                              void* d_out, int out_size, void* d_ws, size_t ws_size,
                              hipStream_t stream)
{
    const float* x    = (const float*)d_in[0];
    const float* wih0 = (const float*)d_in[1];
    const float* whh0 = (const float*)d_in[2];
    const float* bih0 = (const float*)d_in[3];
    const float* bhh0 = (const float*)d_in[4];
    const float* wih1 = (const float*)d_in[5];
    const float* whh1 = (const float*)d_in[6];
    const float* bih1 = (const float*)d_in[7];
    const float* bhh1 = (const float*)d_in[8];
    const float* wih2 = (const float*)d_in[9];
    const float* whh2 = (const float*)d_in[10];
    const float* bih2 = (const float*)d_in[11];
    const float* bhh2 = (const float*)d_in[12];
    const float* fcw  = (const float*)d_in[13];
    const float* fcb  = (const float*)d_in[14];
    float* outp = (float*)d_out;

    const long long R = (long long)BB * TT;      // 524288 rows
    float* pre  = (float*)d_ws;                  // R*256 fp32 = 512 MB
    float* hbuf = pre + R * 256;                 // R*64  fp32 = 128 MB

    const int gemm_grid = (int)(R / 64);         // 8192

    // layer-0 pre-activations (input GEMM, embarrassingly parallel)
    gemm_pre_k<<<gemm_grid, 256, 0, stream>>>(x, wih0, bih0, bhh0, pre, 128);
    // fused 3-layer systolic recurrence
    lstm_fused_k<<<BB, 768, 0, stream>>>(pre, whh0,
                                         wih1, whh1, bih1, bhh1,
                                         wih2, whh2, bih2, bhh2, hbuf);
    // FC epilogue
    fc_k<<<(int)(R / 256), 256, 0, stream>>>(hbuf, fcw, fcb, outp, R);
}

// Round 7
// 9693.001 us; speedup vs baseline: 1.1043x; 1.1043x over previous
//
#include <hip/hip_runtime.h>

#define TT 2048
#define BB 256
#define HID 64

typedef float f32x4 __attribute__((ext_vector_type(4)));

__device__ __forceinline__ float frcp(float x) { return __builtin_amdgcn_rcpf(x); }
__device__ __forceinline__ float fsig(float x) { return frcp(1.f + __expf(-x)); }
// tanh(x) = 1 - 2/(1+e^{2x}) : stable at +/-inf (no inf-inf)
__device__ __forceinline__ float ftanh(float x) { return 1.f - 2.f * frcp(1.f + __expf(2.f * x)); }

// Raw workgroup barrier: waits LDS ops only (lgkmcnt), does NOT drain vmcnt —
// global prefetch loads / h-stores stay in flight across the barrier.
__device__ __forceinline__ void wg_barrier_lds() {
    asm volatile("s_waitcnt lgkmcnt(0)" ::: "memory");
    __builtin_amdgcn_s_barrier();
    asm volatile("" ::: "memory");
}

// Pin 4 f32x4 values into arch VGPRs: the (empty) asm "modifies" them, so the
// compiler cannot rematerialize from memory or park them in AGPRs. (R5-proven.)
#define PIN4(a, b, c, d) asm volatile("" : "+v"(a), "+v"(b), "+v"(c), "+v"(d))

// pre = in(R,K) @ W(256,K)^T + b_ih + b_hh  -> out(R,256)
// block: 256 threads, tile 64 rows x 256 cols, k-chunks of 16.  (layer 0 only)
__global__ __launch_bounds__(256, 2) void gemm_pre_k(
    const float* __restrict__ in, const float* __restrict__ W,
    const float* __restrict__ b_ih, const float* __restrict__ b_hh,
    float* __restrict__ out, int K)
{
    __shared__ __align__(16) float in_s[64][20];   // +4 pad keeps float4 align, breaks conflicts
    __shared__ __align__(16) float w_s[16][256];   // transposed W chunk: w_s[k][g]

    const int tid = threadIdx.x;
    const int tx = tid & 15, ty = tid >> 4;
    const long long row0 = (long long)blockIdx.x * 64;

    float4 bias[4];
    {
        const float4* bi4 = (const float4*)b_ih;
        const float4* bh4 = (const float4*)b_hh;
#pragma unroll
        for (int jj = 0; jj < 4; ++jj) {
            float4 a = bi4[tx * 4 + jj], b = bh4[tx * 4 + jj];
            bias[jj] = make_float4(a.x + b.x, a.y + b.y, a.z + b.z, a.w + b.w);
        }
    }

    float4 acc[4][4];
#pragma unroll
    for (int i = 0; i < 4; ++i)
#pragma unroll
        for (int j = 0; j < 4; ++j) acc[i][j] = make_float4(0.f, 0.f, 0.f, 0.f);

    const int rs = tid >> 2;   // 0..63 staging row
    const int kq = tid & 3;    // 0..3 staging k-quarter

    for (int kc = 0; kc < K; kc += 16) {
        __syncthreads();
        float4 iv = *(const float4*)(in + (row0 + rs) * K + kc + kq * 4);
        *(float4*)(&in_s[rs][kq * 4]) = iv;
        const float* wr = W + (long long)tid * K + kc;
        float4 w0 = ((const float4*)wr)[0];
        float4 w1 = ((const float4*)wr)[1];
        float4 w2 = ((const float4*)wr)[2];
        float4 w3 = ((const float4*)wr)[3];
        w_s[0][tid] = w0.x;  w_s[1][tid] = w0.y;  w_s[2][tid] = w0.z;  w_s[3][tid] = w0.w;
        w_s[4][tid] = w1.x;  w_s[5][tid] = w1.y;  w_s[6][tid] = w1.z;  w_s[7][tid] = w1.w;
        w_s[8][tid] = w2.x;  w_s[9][tid] = w2.y;  w_s[10][tid] = w2.z; w_s[11][tid] = w2.w;
        w_s[12][tid] = w3.x; w_s[13][tid] = w3.y; w_s[14][tid] = w3.z; w_s[15][tid] = w3.w;
        __syncthreads();

#pragma unroll
        for (int k2 = 0; k2 < 4; ++k2) {
            float4 a[4];
#pragma unroll
            for (int i = 0; i < 4; ++i) a[i] = *(const float4*)(&in_s[ty * 4 + i][k2 * 4]);
#pragma unroll
            for (int kk = 0; kk < 4; ++kk) {
                const int k = k2 * 4 + kk;
                float4 wv[4];
#pragma unroll
                for (int jj = 0; jj < 4; ++jj) wv[jj] = *(const float4*)(&w_s[k][tx * 16 + jj * 4]);
#pragma unroll
                for (int i = 0; i < 4; ++i) {
                    const float av = ((const float*)&a[i])[kk];
#pragma unroll
                    for (int jj = 0; jj < 4; ++jj) {
                        acc[i][jj].x += av * wv[jj].x;
                        acc[i][jj].y += av * wv[jj].y;
                        acc[i][jj].z += av * wv[jj].z;
                        acc[i][jj].w += av * wv[jj].w;
                    }
                }
            }
        }
    }

#pragma unroll
    for (int i = 0; i < 4; ++i) {
        float4* op = (float4*)(out + (row0 + ty * 4 + i) * 256 + tx * 16);
#pragma unroll
        for (int jj = 0; jj < 4; ++jj) {
            float4 v = acc[i][jj];
            v.x += bias[jj].x; v.y += bias[jj].y; v.z += bias[jj].z; v.w += bias[jj].w;
            op[jj] = v;
        }
    }
}

// Fused 3-layer systolic recurrence.
//  - one block/batch, 768 threads = 12 waves = 3 layers x 4 gates; lane j owns
//    h-index j. Weight rows W_hh[L][q*64+j] (+ W_ih[L][q*64+j] for L>0) =
//    128 VGPRs/lane, PINNED arch-resident (PIN4) under a 170-reg budget
//    (amdgpu_waves_per_eu(3,3): 12 waves/CU = 3/EU is the real occupancy).
//  - global step s: layer L processes t = s-L (systolic skew); layers 1,2
//    compute W_ih.h in-register -> no standalone GEMMs for them.
//  - ONE lgkm-only barrier/step: activated gates exchanged via double-buffered
//    gx[s&1]; every wave then redundantly updates BOTH its own layer's (c,h)
//    and its input layer's (c,h) shadow state, writing both h-vectors to its
//    PRIVATE LDS slab -> all dot-product h reads are within-wave (no BAR2).
//  - layer-0 pre prefetched 4 steps deep by L0 waves only; vmcnt (prefetch,
//    h store) never drains at a barrier.
__global__ __launch_bounds__(768)
__attribute__((amdgpu_waves_per_eu(3, 3)))
void lstm_fused_k(
    const float* __restrict__ pre,      // [BB][TT][256] layer-0 pre (GEMM+bias)
    const float* __restrict__ whh0,
    const float* __restrict__ wih1, const float* __restrict__ whh1,
    const float* __restrict__ bih1, const float* __restrict__ bhh1,
    const float* __restrict__ wih2, const float* __restrict__ whh2,
    const float* __restrict__ bih2, const float* __restrict__ bhh2,
    float* __restrict__ h_out)          // [BB][TT][64] layer-2 h
{
    __shared__ float gx[2][3][4][HID];            // [s&1][L][q][j] activated gates
    __shared__ __align__(16) float hpriv[12][2][HID]; // [wave][own|prev][j]

    const int tid = threadIdx.x;
    const int wv  = tid >> 6;      // 0..11
    const int L   = wv >> 2;       // layer 0..2
    const int q   = wv & 3;        // gate type: 0=i 1=f 2=g(tanh) 3=o
    const int j   = tid & 63;      // h index
    const int g   = q * HID + j;   // gate row
    const int b   = blockIdx.x;

    // ---- weights into registers (wave-uniform L branches) ----
    f32x4 whh_r[16];
    f32x4 wih_r[16];
    float bias = 0.f;
    {
        const float* whh = (L == 0) ? whh0 : (L == 1 ? whh1 : whh2);
        const f32x4* wr = (const f32x4*)(whh + (long long)g * HID);
#pragma unroll
        for (int k = 0; k < 16; ++k) whh_r[k] = wr[k];
        if (L > 0) {
            const float* wih = (L == 1) ? wih1 : wih2;
            const f32x4* wi = (const f32x4*)(wih + (long long)g * HID);
#pragma unroll
            for (int k = 0; k < 16; ++k) wih_r[k] = wi[k];
            bias = (L == 1) ? (bih1[g] + bhh1[g]) : (bih2[g] + bhh2[g]);
        } else {
#pragma unroll
            for (int k = 0; k < 16; ++k) wih_r[k] = (f32x4)(0.f);
        }
    }

    // private h slabs start at zero (own-wave write; own-wave reads later)
    hpriv[wv][0][j] = 0.f;
    hpriv[wv][1][j] = 0.f;
    float c_own = 0.f, c_prev = 0.f;

    // ---- layer-0 pre prefetch: 4 static slots, L0 waves only ----
    const float* pq = pre + (long long)b * TT * 256 + g;
    float pb4[4] = {0.f, 0.f, 0.f, 0.f};
    if (L == 0) {
#pragma unroll
        for (int u = 0; u < 4; ++u) pb4[u] = pq[u * 256];
    }

    float* hop = h_out + (long long)b * TT * HID + j;
    const bool store_wave = (L == 2) && (q == 0);

    for (int sb = 0; sb < TT + 4; sb += 4) {
        // keep the 128 weight VGPRs arch-resident (no remat, no AGPR parking)
#pragma unroll
        for (int k = 0; k < 16; k += 4) PIN4(whh_r[k], whh_r[k + 1], whh_r[k + 2], whh_r[k + 3]);
#pragma unroll
        for (int k = 0; k < 16; k += 4) PIN4(wih_r[k], wih_r[k + 1], wih_r[k + 2], wih_r[k + 3]);

        const float* pn = pq + (long long)(sb + 4) * 256;   // reload base (s+4)
#pragma unroll
        for (int u = 0; u < 4; ++u) {
            const int s = sb + u;
            const int t = s - L;
            const bool actL = (t >= 0) && (t < TT);   // wave-uniform

            if (actL) {
                f32x4 a0 = (f32x4)(0.f), a1 = (f32x4)(0.f);
                float gA;
                if (L == 0) {
                    const f32x4* hon = (const f32x4*)(&hpriv[wv][0][0]);
#pragma unroll
                    for (int k = 0; k < 16; k += 2) {
                        a0 += whh_r[k] * hon[k];
                        a1 += whh_r[k + 1] * hon[k + 1];
                    }
                    gA = pb4[u];
                    if (s + 4 < TT) pb4[u] = pn[u * 256];   // stays in flight
                } else {
                    const f32x4* hon = (const f32x4*)(&hpriv[wv][0][0]);
                    const f32x4* hin = (const f32x4*)(&hpriv[wv][1][0]);
#pragma unroll
                    for (int k = 0; k < 16; ++k) {
                        a0 += wih_r[k] * hin[k];     // wave-uniform broadcast
                        a1 += whh_r[k] * hon[k];
                    }
                    gA = bias;
                }
                f32x4 asum = a0 + a1;
                gA += (asum.x + asum.y) + (asum.z + asum.w);
                float a = (q == 2) ? ftanh(gA) : fsig(gA);
                gx[s & 1][L][q][j] = a;              // conflict-free
            }

            wg_barrier_lds();   // gates of step s visible; vmcnt in flight

            // own-layer update (gates produced this step)
            if (actL) {
                float iv = gx[s & 1][L][0][j];
                float fv = gx[s & 1][L][1][j];
                float gv = gx[s & 1][L][2][j];
                float ov = gx[s & 1][L][3][j];
                c_own = fv * c_own + iv * gv;
                float h = ov * ftanh(c_own);
                hpriv[wv][0][j] = h;
                if (store_wave) hop[(long long)t * HID] = h;  // fire-and-forget
            }
            // input-layer shadow update (L>0): track layer L-1's state
            if (L > 0) {
                const int tp = s - (L - 1);
                if (tp >= 0 && tp < TT) {
                    float iv = gx[s & 1][L - 1][0][j];
                    float fv = gx[s & 1][L - 1][1][j];
                    float gv = gx[s & 1][L - 1][2][j];
                    float ov = gx[s & 1][L - 1][3][j];
                    c_prev = fv * c_prev + iv * gv;
                    hpriv[wv][1][j] = ov * ftanh(c_prev);
                }
            }
            // next step's dot reads hpriv[wv] — same-wave DS ordering
        }
    }
}

// out(r) = h(r,:) . fc_w + fc_b   — trivial GEMV epilogue, off the critical path
__global__ __launch_bounds__(256) void fc_k(
    const float* __restrict__ h, const float* __restrict__ fc_w,
    const float* __restrict__ fc_b, float* __restrict__ out, long long R)
{
    __shared__ __align__(16) float w_s[HID];
    if (threadIdx.x < HID) w_s[threadIdx.x] = fc_w[threadIdx.x];
    __syncthreads();

    long long r = (long long)blockIdx.x * 256 + threadIdx.x;
    if (r >= R) return;

    const float4* hp = (const float4*)(h + r * HID);
    const float4* wp = (const float4*)w_s;
    float s0 = 0.f, s1 = 0.f, s2 = 0.f, s3 = 0.f;
#pragma unroll
    for (int k = 0; k < 16; ++k) {
        float4 hvv = hp[k];
        float4 wvv = wp[k];      // wave-uniform LDS broadcast
        s0 += hvv.x * wvv.x;
        s1 += hvv.y * wvv.y;
        s2 += hvv.z * wvv.z;
        s3 += hvv.w * wvv.w;
    }
    out[r] = (s0 + s1) + (s2 + s3) + fc_b[0];
}

extern "C" void kernel_launch(void* const* d_in, const int* in_sizes, int n_in,
                              void* d_out, int out_size, void* d_ws, size_t ws_size,
                              hipStream_t stream)
{
    const float* x    = (const float*)d_in[0];
    const float* wih0 = (const float*)d_in[1];
    const float* whh0 = (const float*)d_in[2];
    const float* bih0 = (const float*)d_in[3];
    const float* bhh0 = (const float*)d_in[4];
    const float* wih1 = (const float*)d_in[5];
    const float* whh1 = (const float*)d_in[6];
    const float* bih1 = (const float*)d_in[7];
    const float* bhh1 = (const float*)d_in[8];
    const float* wih2 = (const float*)d_in[9];
    const float* whh2 = (const float*)d_in[10];
    const float* bih2 = (const float*)d_in[11];
    const float* bhh2 = (const float*)d_in[12];
    const float* fcw  = (const float*)d_in[13];
    const float* fcb  = (const float*)d_in[14];
    float* outp = (float*)d_out;

    const long long R = (long long)BB * TT;      // 524288 rows
    float* pre  = (float*)d_ws;                  // R*256 fp32 = 512 MB
    float* hbuf = pre + R * 256;                 // R*64  fp32 = 128 MB

    const int gemm_grid = (int)(R / 64);         // 8192

    // layer-0 pre-activations (input GEMM, embarrassingly parallel)
    gemm_pre_k<<<gemm_grid, 256, 0, stream>>>(x, wih0, bih0, bhh0, pre, 128);
    // fused 3-layer systolic recurrence
    lstm_fused_k<<<BB, 768, 0, stream>>>(pre, whh0,
                                         wih1, whh1, bih1, bhh1,
                                         wih2, whh2, bih2, bhh2, hbuf);
    // FC epilogue
    fc_k<<<(int)(R / 256), 256, 0, stream>>>(hbuf, fcw, fcb, outp, R);
}